// Round 9
// baseline (365.556 us; speedup 1.0000x reference)
//
#include <hip/hip_runtime.h>
#include <hip/hip_bf16.h>
#include <math.h>

#define B_ 2
#define L_ 2048
#define DM_ 1024
#define DC_ 512
#define NH_ 8
#define DH_ 64
#define MR_ (B_*L_)   // 4096 rows
#define BH_ (B_*NH_)  // 16

typedef unsigned short u16;
typedef unsigned int u32;
typedef __attribute__((ext_vector_type(8))) short bf16x8;
typedef __attribute__((ext_vector_type(4))) float f32x4;

static __device__ __forceinline__ u16 f2bf(float x) {
  union { float f; u32 u; } v; v.f = x;
  u32 r = (v.u + 0x7fffu + ((v.u >> 16) & 1u)) >> 16;  // RNE
  return (u16)r;
}
static __device__ __forceinline__ float bf2f(u16 x) {
  union { u32 u; float f; } v; v.u = ((u32)x) << 16;
  return v.f;
}

// ---------------------------------------------------------------------------
// One-shot fp32 -> bf16 conversion: x1, Wq, Wk, Wst, Wout.
// ---------------------------------------------------------------------------
__global__ __launch_bounds__(256) void cvt_k(
    const float* __restrict__ src,
    const float* __restrict__ Wq, const float* __restrict__ Wk,
    const float* __restrict__ Wst, const float* __restrict__ Wout,
    u16* __restrict__ x1b, u16* __restrict__ Wqb, u16* __restrict__ Wkb,
    u16* __restrict__ Wstb, u16* __restrict__ Woutb)
{
  int v = blockIdx.x * 256 + threadIdx.x;
  if (v < 524288) {
    const int m = v >> 7, c = (v & 127) << 2;
    float4 f = *(const float4*)(src + (size_t)m * DM_ + c);
    *(ushort4*)(x1b + (size_t)m * DC_ + c) =
        make_ushort4(f2bf(f.x), f2bf(f.y), f2bf(f.z), f2bf(f.w));
    return;
  }
  v -= 524288;
  const float* sp; u16* dp;
  if (v < 65536)       { sp = Wq;   dp = Wqb; }
  else if (v < 131072) { sp = Wk;   dp = Wkb;   v -= 65536; }
  else if (v < 196608) { sp = Wst;  dp = Wstb;  v -= 131072; }
  else                 { sp = Wout; dp = Woutb; v -= 196608; }
  float4 f = *(const float4*)(sp + (size_t)v * 4);
  *(ushort4*)(dp + (size_t)v * 4) =
      make_ushort4(f2bf(f.x), f2bf(f.y), f2bf(f.z), f2bf(f.w));
}

// ---------------------------------------------------------------------------
// K transpose: KhT[bh][d][m] from Kh[bh][m][d]. Block = (bh, 64-m tile).
// ---------------------------------------------------------------------------
__global__ __launch_bounds__(256) void tr_k(const u16* __restrict__ Kh,
                                            u16* __restrict__ KhT)
{
  __shared__ u16 T[64*72];
  const int tid = threadIdx.x;
  const int bh = blockIdx.x >> 5, mt = blockIdx.x & 31;
  const int m0 = mt << 6;
  const u16* Kb = Kh + ((size_t)bh * L_ + m0) * DH_;
  const int r = tid >> 2, c = (tid & 3) << 4;
  *(bf16x8*)&T[r*72 + c]     = *(const bf16x8*)(Kb + (size_t)r * DH_ + c);
  *(bf16x8*)&T[r*72 + c + 8] = *(const bf16x8*)(Kb + (size_t)r * DH_ + c + 8);
  __syncthreads();
  const int d = tid >> 2, mc = (tid & 3) << 4;
  bf16x8 v0, v1;
#pragma unroll
  for (int i = 0; i < 8; ++i) {
    v0[i] = (short)T[(mc + i)*72 + d];
    v1[i] = (short)T[(mc + 8 + i)*72 + d];
  }
  u16* dst = KhT + ((size_t)bh * DH_ + d) * L_ + m0 + mc;
  *(bf16x8*)dst = v0;
  *(bf16x8*)(dst + 8) = v1;
}

// ---------------------------------------------------------------------------
// bf16 MFMA GEMM: C = A @ W^T + bias. (unchanged)
// ---------------------------------------------------------------------------
template<int MODE, int BN>
__global__ __launch_bounds__(256) void mgemm_k(
    const u16* __restrict__ A, const u16* __restrict__ A2,
    const u16* __restrict__ W, const float* __restrict__ bias,
    const float* __restrict__ src, u16* __restrict__ Ob,
    float* __restrict__ Of, int Ndim, int Kdim)
{
  constexpr int MF = (BN == 128) ? 4 : 2;
  constexpr int WC = BN / 64;
  __shared__ u16 As[128 * 40];
  __shared__ u16 Ws[BN * 40];
  const int tid = threadIdx.x;
  const int wid = tid >> 6, lane = tid & 63;
  const int lr = lane & 15, lg = lane >> 4;
  const int wr = wid / WC, wc = wid % WC;
  const int m0 = blockIdx.y << 7;
  const int n0 = blockIdx.x * BN;

  f32x4 acc[MF][4];
#pragma unroll
  for (int mi = 0; mi < MF; ++mi)
#pragma unroll
    for (int ni = 0; ni < 4; ++ni)
      acc[mi][ni] = (f32x4){0.f, 0.f, 0.f, 0.f};

  for (int k0 = 0; k0 < Kdim; k0 += 32) {
    {
      const int row = tid >> 1, seg = (tid & 1) << 4;
      const u16* ap;
      if (MODE == 2)
        ap = (k0 < 512) ? A  + (size_t)(m0 + row) * 512 + k0 + seg
                        : A2 + (size_t)(m0 + row) * 512 + (k0 - 512) + seg;
      else
        ap = A + (size_t)(m0 + row) * Kdim + k0 + seg;
      *(bf16x8*)&As[row * 40 + seg]     = *(const bf16x8*)ap;
      *(bf16x8*)&As[row * 40 + seg + 8] = *(const bf16x8*)(ap + 8);
    }
    if (BN == 128) {
      const int row = tid >> 1, seg = (tid & 1) << 4;
      const u16* wp = W + (size_t)(n0 + row) * Kdim + k0 + seg;
      *(bf16x8*)&Ws[row * 40 + seg]     = *(const bf16x8*)wp;
      *(bf16x8*)&Ws[row * 40 + seg + 8] = *(const bf16x8*)(wp + 8);
    } else {
      const int row = tid >> 2, seg = (tid & 3) << 3;
      *(bf16x8*)&Ws[row * 40 + seg] =
          *(const bf16x8*)(W + (size_t)(n0 + row) * Kdim + k0 + seg);
    }
    __syncthreads();
    bf16x8 af[MF], bfr[4];
#pragma unroll
    for (int mi = 0; mi < MF; ++mi)
      af[mi] = *(bf16x8*)&As[(wr * (MF * 16) + mi * 16 + lr) * 40 + lg * 8];
#pragma unroll
    for (int ni = 0; ni < 4; ++ni)
      bfr[ni] = *(bf16x8*)&Ws[(wc * 64 + ni * 16 + lr) * 40 + lg * 8];
#pragma unroll
    for (int mi = 0; mi < MF; ++mi)
#pragma unroll
      for (int ni = 0; ni < 4; ++ni)
        acc[mi][ni] = __builtin_amdgcn_mfma_f32_16x16x32_bf16(
            af[mi], bfr[ni], acc[mi][ni], 0, 0, 0);
    __syncthreads();
  }

#pragma unroll
  for (int mi = 0; mi < MF; ++mi)
#pragma unroll
    for (int ni = 0; ni < 4; ++ni)
#pragma unroll
      for (int r = 0; r < 4; ++r) {
        const int m = m0 + wr * (MF * 16) + mi * 16 + lg * 4 + r;
        const int n = n0 + wc * 64 + ni * 16 + lr;
        const float v = acc[mi][ni][r] + bias[n];
        if (MODE == 0) {
          const int b = m >> 11, l = m & (L_ - 1), h = n >> 6, d = n & (DH_ - 1);
          Ob[((size_t)(b * NH_ + h) * L_ + l) * DH_ + d] = f2bf(v);
        } else if (MODE == 1) {
          const float x2 = src[(size_t)m * DM_ + DC_ + n];
          const float s = 1.f / (1.f + __expf(-v));
          Ob[(size_t)m * DC_ + n] = f2bf(s * tanhf(x2) + (1.f - s) * x2);
        } else {
          Of[(size_t)m * Ndim + n] = v;
        }
      }
}

// ---------------------------------------------------------------------------
// Saliency conv1d v2: 512 blocks (8 l x B), 256 thr = 8l x 8h x 4 c-quarters.
// Skewed LDS (stride 532, col = c + c/32) -> conflict-free broadcast reads.
// ---------------------------------------------------------------------------
__global__ __launch_bounds__(256) void conv_k(
    const float* __restrict__ src, const float* __restrict__ cw,
    const float* __restrict__ cb, float* __restrict__ sal)
{
  __shared__ float xs[10][532];
  __shared__ float part[8][8][4];
  const int b = blockIdx.y;
  const int l0 = blockIdx.x << 3;
  const int tid = threadIdx.x;
  const int li = tid >> 5;          // 0..7
  const int h  = (tid >> 2) & 7;    // 0..7
  const int cq = tid & 3;           // 0..3
  // stage rows l0-1 .. l0+8 (10 rows x 512 c), skewed columns
  for (int t = tid; t < 10*128; t += 256) {
    const int r = t >> 7, c4 = (t & 127) << 2;
    const int l = l0 - 1 + r;
    float4 v = make_float4(0.f, 0.f, 0.f, 0.f);
    if (l >= 0 && l < L_)
      v = *(const float4*)(src + (size_t)(b*L_ + l) * DM_ + c4);
    *(float4*)&xs[r][c4 + (c4 >> 5)] = v;
  }
  __syncthreads();
  float acc = 0.f;
  const int cbase = cq << 7;
#pragma unroll 4
  for (int c = 0; c < 128; ++c) {
    const int cc = cbase + c;
    const int col = cc + (cc >> 5);
    const float* w = cw + ((size_t)h * DC_ + cc) * 3;
    acc += xs[li+0][col]*w[0] + xs[li+1][col]*w[1] + xs[li+2][col]*w[2];
  }
  part[li][h][cq] = acc;
  __syncthreads();
  if (tid < 64) {
    const int l2 = tid >> 3, h2 = tid & 7;
    const float s = cb[h2] + part[l2][h2][0] + part[l2][h2][1]
                           + part[l2][h2][2] + part[l2][h2][3];
    sal[(size_t)(b*NH_ + h2) * L_ + l0 + l2] = s;
  }
}

// ---------------------------------------------------------------------------
// MFMA attention v4: ZERO barriers after sal staging. QK B-frags from global
// K rows; PV B-frags from global KhT rows (both coalesced 16B/lane, L2-hot
// via XCD swizzle). Ps is same-wave LDS only (in-order wave semantics make
// write->read safe without barriers — proven in r8). Waves fully independent.
// ---------------------------------------------------------------------------
__global__ __launch_bounds__(256) void attn_k(
    const u16* __restrict__ Qh, const u16* __restrict__ Kh,
    const u16* __restrict__ KhT, const float* __restrict__ sal,
    float* __restrict__ attn, u16* __restrict__ ctxb)
{
  __shared__ u16 Ps[64*72];
  __shared__ float sal_s[L_];

  const int tid = threadIdx.x;
  const int wid = tid >> 6, lane = tid & 63;
  const int lr = lane & 15, lg = lane >> 4;
  // XCD-bijective swizzle: 512 blocks = 8 xcd x 64; same-bh blocks cluster
  const int lin = blockIdx.x;
  const int swz = (lin & 7) * 64 + (lin >> 3);
  const int bh = swz >> 5, q0 = (swz & 31) << 6;

  const u16* Kb  = Kh  + (size_t)bh * L_ * DH_;
  const u16* KTb = KhT + (size_t)bh * DH_ * L_;

  // stage sal row (2048 f32 = 8KB) once
  {
    const float4* sp = (const float4*)(sal + (size_t)bh * L_);
    float4* dp = (float4*)sal_s;
#pragma unroll
    for (int i = 0; i < 2; ++i)
      dp[tid + i*256] = sp[tid + i*256];
  }
  // Q frags direct from global
  const u16* Qp = Qh + ((size_t)bh * L_ + q0) * DH_;
  bf16x8 qf[2];
  qf[0] = *(const bf16x8*)(Qp + (size_t)(wid*16 + lr) * DH_ + lg*8);
  qf[1] = *(const bf16x8*)(Qp + (size_t)(wid*16 + lr) * DH_ + 32 + lg*8);
  __syncthreads();  // sal_s visible (only barrier in the kernel)

  // ================= sweep 1: rowsums (global-direct, barrier-free) ========
  float rs[4] = {0.f, 0.f, 0.f, 0.f};
#pragma unroll 2
  for (int m0 = 0; m0 < L_; m0 += 64) {
#pragma unroll
    for (int ms = 0; ms < 4; ++ms) {
      f32x4 acc = {0.f, 0.f, 0.f, 0.f};
#pragma unroll
      for (int ks = 0; ks < 2; ++ks) {
        bf16x8 kf = *(const bf16x8*)(Kb + (size_t)(m0 + ms*16 + lr) * DH_ + ks*32 + lg*8);
        acc = __builtin_amdgcn_mfma_f32_16x16x32_bf16(qf[ks], kf, acc, 0, 0, 0);
      }
      const float sl = sal_s[m0 + ms*16 + lr];
#pragma unroll
      for (int r = 0; r < 4; ++r)
        rs[r] += __expf(fmaf(acc[r], 0.125f, sl));
    }
  }
  // reduce over 16 col-lanes -> invS in every lane of the row
#pragma unroll
  for (int r = 0; r < 4; ++r) {
    float v = rs[r];
    v += __shfl_xor(v, 1); v += __shfl_xor(v, 2);
    v += __shfl_xor(v, 4); v += __shfl_xor(v, 8);
    rs[r] = 1.0f / v;
  }

  // ================= sweep 2: attn store + PV (barrier-free) ===============
  f32x4 pvacc[4] = {{0.f,0.f,0.f,0.f},{0.f,0.f,0.f,0.f},
                    {0.f,0.f,0.f,0.f},{0.f,0.f,0.f,0.f}};
  u16* PsW = &Ps[0];
#pragma unroll 2
  for (int t = 0; t < 32; ++t) {
    const int m0 = t << 6;
    // QK^T (B-frags from global) + normalized p -> Ps (same-wave strip)
#pragma unroll
    for (int ms = 0; ms < 4; ++ms) {
      f32x4 acc = {0.f, 0.f, 0.f, 0.f};
#pragma unroll
      for (int ks = 0; ks < 2; ++ks) {
        bf16x8 kf = *(const bf16x8*)(Kb + (size_t)(m0 + ms*16 + lr) * DH_ + ks*32 + lg*8);
        acc = __builtin_amdgcn_mfma_f32_16x16x32_bf16(qf[ks], kf, acc, 0, 0, 0);
      }
      const float sl = sal_s[m0 + ms*16 + lr];
#pragma unroll
      for (int r = 0; r < 4; ++r) {
        const float ph = __expf(fmaf(acc[r], 0.125f, sl)) * rs[r];
        PsW[(wid*16 + lg*4 + r)*72 + ms*16 + lr] = f2bf(ph);
      }
    }
    // attn store: own strip from Ps, coalesced float4 stores
    {
      const int qr = lane >> 2;            // 0..15
      const int mseg = (lane & 3) << 4;    // 0,16,32,48
      bf16x8 v0 = *(bf16x8*)&PsW[(wid*16 + qr)*72 + mseg];
      bf16x8 v1 = *(bf16x8*)&PsW[(wid*16 + qr)*72 + mseg + 8];
      float* dst = attn + ((size_t)bh * L_ + q0 + wid*16 + qr) * L_ + m0 + mseg;
#pragma unroll
      for (int u = 0; u < 2; ++u) {
        bf16x8 v = u ? v1 : v0;
        float4 f0 = make_float4(bf2f((u16)v[0]), bf2f((u16)v[1]),
                                bf2f((u16)v[2]), bf2f((u16)v[3]));
        float4 f1 = make_float4(bf2f((u16)v[4]), bf2f((u16)v[5]),
                                bf2f((u16)v[6]), bf2f((u16)v[7]));
        *(float4*)(dst + u*8)     = f0;
        *(float4*)(dst + u*8 + 4) = f1;
      }
    }
    // PV: ctx += P @ K  (A = Ps rows, B = KhT rows from global)
#pragma unroll
    for (int ks = 0; ks < 2; ++ks) {
      bf16x8 pa = *(bf16x8*)&PsW[(wid*16 + lr)*72 + ks*32 + lg*8];
#pragma unroll
      for (int ds = 0; ds < 4; ++ds) {
        bf16x8 kb = *(const bf16x8*)(KTb + (size_t)(ds*16 + lr) * L_ + m0 + ks*32 + lg*8);
        pvacc[ds] = __builtin_amdgcn_mfma_f32_16x16x32_bf16(pa, kb, pvacc[ds], 0, 0, 0);
      }
    }
  }
  // ctx store [b, l, h*64+d] as bf16
  const int b = bh >> 3, h = bh & 7;
#pragma unroll
  for (int ds = 0; ds < 4; ++ds)
#pragma unroll
    for (int r = 0; r < 4; ++r)
      ctxb[((size_t)(b*L_ + q0 + wid*16 + lg*4 + r)) * DC_ + h*DH_ + ds*16 + lr] =
          f2bf(pvacc[ds][r]);
}

// ---------------------------------------------------------------------------
extern "C" void kernel_launch(void* const* d_in, const int* in_sizes, int n_in,
                              void* d_out, int out_size, void* d_ws, size_t ws_size,
                              hipStream_t stream)
{
  const float* src   = (const float*)d_in[0];
  const float* Wq    = (const float*)d_in[1];
  const float* bq    = (const float*)d_in[2];
  const float* Wk    = (const float*)d_in[3];
  const float* bk    = (const float*)d_in[4];
  const float* convw = (const float*)d_in[5];
  const float* convb = (const float*)d_in[6];
  const float* Wst   = (const float*)d_in[7];
  const float* bst   = (const float*)d_in[8];
  const float* Wout  = (const float*)d_in[9];
  const float* bout  = (const float*)d_in[10];

  float* out  = (float*)d_out;                 // fp32: reference output dtype
  float* attn = out + (size_t)MR_ * DM_;       // output (4,194,304), then attn (67,108,864)

  u16*   x1b   = (u16*)d_ws;                    // [4096][512]
  u16*   Qh    = x1b   + (size_t)MR_ * DC_;     // [16][2048][64]
  u16*   Kh    = Qh    + (size_t)BH_ * L_ * DH_;
  u16*   KhT   = Kh    + (size_t)BH_ * L_ * DH_;// [16][64][2048]
  u16*   ctxb  = KhT   + (size_t)BH_ * DH_ * L_;// [4096][512]
  u16*   y2b   = ctxb  + (size_t)MR_ * DC_;     // [4096][512]
  u16*   Wqb   = y2b   + (size_t)MR_ * DC_;     // [512][512]
  u16*   Wkb   = Wqb   + (size_t)DC_ * DC_;
  u16*   Wstb  = Wkb   + (size_t)DC_ * DC_;
  u16*   Woutb = Wstb  + (size_t)DC_ * DC_;     // [1024][1024]
  float* salb  = (float*)(Woutb + (size_t)DM_ * DM_); // [16][2048]

  (void)in_sizes; (void)n_in; (void)out_size; (void)ws_size;

  cvt_k<<<dim3(3840), 256, 0, stream>>>(src, Wq, Wk, Wst, Wout,
                                        x1b, Wqb, Wkb, Wstb, Woutb);
  mgemm_k<0,64><<<dim3(8, 32), 256, 0, stream>>>(x1b, nullptr, Wqb, bq, nullptr, Qh, nullptr, DC_, DC_);
  mgemm_k<0,64><<<dim3(8, 32), 256, 0, stream>>>(x1b, nullptr, Wkb, bk, nullptr, Kh, nullptr, DC_, DC_);
  tr_k<<<dim3(512), 256, 0, stream>>>(Kh, KhT);
  conv_k<<<dim3(L_/8, B_), 256, 0, stream>>>(src, convw, convb, salb);
  attn_k<<<dim3(512), 256, 0, stream>>>(Qh, Kh, KhT, salb, attn, ctxb);
  mgemm_k<1,64><<<dim3(8, 32), 256, 0, stream>>>(ctxb, nullptr, Wstb, bst, src, y2b, nullptr, DC_, DC_);
  mgemm_k<2,128><<<dim3(8, 32), 256, 0, stream>>>(x1b, y2b, Woutb, bout, nullptr, nullptr, out, DM_, DM_);
}

// Round 10
// 248.036 us; speedup vs baseline: 1.4738x; 1.4738x over previous
//
#include <hip/hip_runtime.h>
#include <hip/hip_bf16.h>
#include <math.h>

#define B_ 2
#define L_ 2048
#define DM_ 1024
#define DC_ 512
#define NH_ 8
#define DH_ 64
#define MR_ (B_*L_)   // 4096 rows
#define BH_ (B_*NH_)  // 16

typedef unsigned short u16;
typedef unsigned int u32;
typedef __attribute__((ext_vector_type(8))) short bf16x8;
typedef __attribute__((ext_vector_type(4))) float f32x4;

static __device__ __forceinline__ u16 f2bf(float x) {
  union { float f; u32 u; } v; v.f = x;
  u32 r = (v.u + 0x7fffu + ((v.u >> 16) & 1u)) >> 16;  // RNE
  return (u16)r;
}
static __device__ __forceinline__ float bf2f(u16 x) {
  union { u32 u; float f; } v; v.u = ((u32)x) << 16;
  return v.f;
}

// ---------------------------------------------------------------------------
// One-shot fp32 -> bf16 conversion: x1, Wq, Wk, Wst, Wout.
// ---------------------------------------------------------------------------
__global__ __launch_bounds__(256) void cvt_k(
    const float* __restrict__ src,
    const float* __restrict__ Wq, const float* __restrict__ Wk,
    const float* __restrict__ Wst, const float* __restrict__ Wout,
    u16* __restrict__ x1b, u16* __restrict__ Wqb, u16* __restrict__ Wkb,
    u16* __restrict__ Wstb, u16* __restrict__ Woutb)
{
  int v = blockIdx.x * 256 + threadIdx.x;
  if (v < 524288) {
    const int m = v >> 7, c = (v & 127) << 2;
    float4 f = *(const float4*)(src + (size_t)m * DM_ + c);
    *(ushort4*)(x1b + (size_t)m * DC_ + c) =
        make_ushort4(f2bf(f.x), f2bf(f.y), f2bf(f.z), f2bf(f.w));
    return;
  }
  v -= 524288;
  const float* sp; u16* dp;
  if (v < 65536)       { sp = Wq;   dp = Wqb; }
  else if (v < 131072) { sp = Wk;   dp = Wkb;   v -= 65536; }
  else if (v < 196608) { sp = Wst;  dp = Wstb;  v -= 131072; }
  else                 { sp = Wout; dp = Woutb; v -= 196608; }
  float4 f = *(const float4*)(sp + (size_t)v * 4);
  *(ushort4*)(dp + (size_t)v * 4) =
      make_ushort4(f2bf(f.x), f2bf(f.y), f2bf(f.z), f2bf(f.w));
}

// ---------------------------------------------------------------------------
// Fragmentize K: from Kh[bh][m][d] build
//   Kf[bh][mt][ks][lane] (QK B-frags)  — IN PLACE over Kh (same 8KB region)
//   Gf[bh][ds][t][ks][lane] (PV B-frags = K^T frags)
// lane = lr + 16*lg; Kf value = K[mt*16+lr][ks*32+lg*8 .. +8]
//                    Gf value[j] = K[t*64+ks*32+lg*8+j][ds*16+lr]
// Block = (bh, 64-row m-block). All frag loads in attn_k become
// base + lane*16B  -> one coalesced 1KB dwordx4 per wave.
// ---------------------------------------------------------------------------
__global__ __launch_bounds__(256) void frag_k(const u16* __restrict__ Kh,
                                              u16* __restrict__ Kf,
                                              u16* __restrict__ Gf)
{
  __shared__ u16 T[64*72];
  const int tid = threadIdx.x;
  const int bh = blockIdx.x >> 5, mblk = blockIdx.x & 31;
  const int m0 = mblk << 6;
  const u16* Kb = Kh + ((size_t)bh * L_ + m0) * DH_;
  {
    const int r = tid >> 2, c = (tid & 3) << 4;
    *(bf16x8*)&T[r*72 + c]     = *(const bf16x8*)(Kb + (size_t)r * DH_ + c);
    *(bf16x8*)&T[r*72 + c + 8] = *(const bf16x8*)(Kb + (size_t)r * DH_ + c + 8);
  }
  __syncthreads();
  // Kf: 512 slots (mt_l, ks, lane), 2 per thread. In-place safe (LDS-staged).
#pragma unroll
  for (int i = 0; i < 2; ++i) {
    const int s = tid + (i << 8);
    const int mt_l = s >> 7, ks = (s >> 6) & 1, lane = s & 63;
    const int lr = lane & 15, lg = lane >> 4;
    bf16x8 v = *(bf16x8*)&T[(mt_l*16 + lr)*72 + ks*32 + lg*8];
    *(bf16x8*)(Kf + ((size_t)((bh*128 + mblk*4 + mt_l)*2 + ks)*64 + lane)*8) = v;
  }
  // Gf: 512 slots (ds, ks, lane), 2 per thread; column gathers from T.
#pragma unroll
  for (int i = 0; i < 2; ++i) {
    const int s = tid + (i << 8);
    const int ds = s >> 7, ks = (s >> 6) & 1, lane = s & 63;
    const int lr = lane & 15, lg = lane >> 4;
    bf16x8 v;
#pragma unroll
    for (int j = 0; j < 8; ++j)
      v[j] = (short)T[(ks*32 + lg*8 + j)*72 + ds*16 + lr];
    *(bf16x8*)(Gf + ((size_t)(((bh*4 + ds)*32 + mblk)*2 + ks)*64 + lane)*8) = v;
  }
}

// ---------------------------------------------------------------------------
// bf16 MFMA GEMM: C = A @ W^T + bias. (unchanged)
// ---------------------------------------------------------------------------
template<int MODE, int BN>
__global__ __launch_bounds__(256) void mgemm_k(
    const u16* __restrict__ A, const u16* __restrict__ A2,
    const u16* __restrict__ W, const float* __restrict__ bias,
    const float* __restrict__ src, u16* __restrict__ Ob,
    float* __restrict__ Of, int Ndim, int Kdim)
{
  constexpr int MF = (BN == 128) ? 4 : 2;
  constexpr int WC = BN / 64;
  __shared__ u16 As[128 * 40];
  __shared__ u16 Ws[BN * 40];
  const int tid = threadIdx.x;
  const int wid = tid >> 6, lane = tid & 63;
  const int lr = lane & 15, lg = lane >> 4;
  const int wr = wid / WC, wc = wid % WC;
  const int m0 = blockIdx.y << 7;
  const int n0 = blockIdx.x * BN;

  f32x4 acc[MF][4];
#pragma unroll
  for (int mi = 0; mi < MF; ++mi)
#pragma unroll
    for (int ni = 0; ni < 4; ++ni)
      acc[mi][ni] = (f32x4){0.f, 0.f, 0.f, 0.f};

  for (int k0 = 0; k0 < Kdim; k0 += 32) {
    {
      const int row = tid >> 1, seg = (tid & 1) << 4;
      const u16* ap;
      if (MODE == 2)
        ap = (k0 < 512) ? A  + (size_t)(m0 + row) * 512 + k0 + seg
                        : A2 + (size_t)(m0 + row) * 512 + (k0 - 512) + seg;
      else
        ap = A + (size_t)(m0 + row) * Kdim + k0 + seg;
      *(bf16x8*)&As[row * 40 + seg]     = *(const bf16x8*)ap;
      *(bf16x8*)&As[row * 40 + seg + 8] = *(const bf16x8*)(ap + 8);
    }
    if (BN == 128) {
      const int row = tid >> 1, seg = (tid & 1) << 4;
      const u16* wp = W + (size_t)(n0 + row) * Kdim + k0 + seg;
      *(bf16x8*)&Ws[row * 40 + seg]     = *(const bf16x8*)wp;
      *(bf16x8*)&Ws[row * 40 + seg + 8] = *(const bf16x8*)(wp + 8);
    } else {
      const int row = tid >> 2, seg = (tid & 3) << 3;
      *(bf16x8*)&Ws[row * 40 + seg] =
          *(const bf16x8*)(W + (size_t)(n0 + row) * Kdim + k0 + seg);
    }
    __syncthreads();
    bf16x8 af[MF], bfr[4];
#pragma unroll
    for (int mi = 0; mi < MF; ++mi)
      af[mi] = *(bf16x8*)&As[(wr * (MF * 16) + mi * 16 + lr) * 40 + lg * 8];
#pragma unroll
    for (int ni = 0; ni < 4; ++ni)
      bfr[ni] = *(bf16x8*)&Ws[(wc * 64 + ni * 16 + lr) * 40 + lg * 8];
#pragma unroll
    for (int mi = 0; mi < MF; ++mi)
#pragma unroll
      for (int ni = 0; ni < 4; ++ni)
        acc[mi][ni] = __builtin_amdgcn_mfma_f32_16x16x32_bf16(
            af[mi], bfr[ni], acc[mi][ni], 0, 0, 0);
    __syncthreads();
  }

#pragma unroll
  for (int mi = 0; mi < MF; ++mi)
#pragma unroll
    for (int ni = 0; ni < 4; ++ni)
#pragma unroll
      for (int r = 0; r < 4; ++r) {
        const int m = m0 + wr * (MF * 16) + mi * 16 + lg * 4 + r;
        const int n = n0 + wc * 64 + ni * 16 + lr;
        const float v = acc[mi][ni][r] + bias[n];
        if (MODE == 0) {
          const int b = m >> 11, l = m & (L_ - 1), h = n >> 6, d = n & (DH_ - 1);
          Ob[((size_t)(b * NH_ + h) * L_ + l) * DH_ + d] = f2bf(v);
        } else if (MODE == 1) {
          const float x2 = src[(size_t)m * DM_ + DC_ + n];
          const float s = 1.f / (1.f + __expf(-v));
          Ob[(size_t)m * DC_ + n] = f2bf(s * tanhf(x2) + (1.f - s) * x2);
        } else {
          Of[(size_t)m * Ndim + n] = v;
        }
      }
}

// ---------------------------------------------------------------------------
// Saliency conv1d v2 (unchanged from round 9)
// ---------------------------------------------------------------------------
__global__ __launch_bounds__(256) void conv_k(
    const float* __restrict__ src, const float* __restrict__ cw,
    const float* __restrict__ cb, float* __restrict__ sal)
{
  __shared__ float xs[10][532];
  __shared__ float part[8][8][4];
  const int b = blockIdx.y;
  const int l0 = blockIdx.x << 3;
  const int tid = threadIdx.x;
  const int li = tid >> 5;
  const int h  = (tid >> 2) & 7;
  const int cq = tid & 3;
  for (int t = tid; t < 10*128; t += 256) {
    const int r = t >> 7, c4 = (t & 127) << 2;
    const int l = l0 - 1 + r;
    float4 v = make_float4(0.f, 0.f, 0.f, 0.f);
    if (l >= 0 && l < L_)
      v = *(const float4*)(src + (size_t)(b*L_ + l) * DM_ + c4);
    *(float4*)&xs[r][c4 + (c4 >> 5)] = v;
  }
  __syncthreads();
  float acc = 0.f;
  const int cbase = cq << 7;
#pragma unroll 4
  for (int c = 0; c < 128; ++c) {
    const int cc = cbase + c;
    const int col = cc + (cc >> 5);
    const float* w = cw + ((size_t)h * DC_ + cc) * 3;
    acc += xs[li+0][col]*w[0] + xs[li+1][col]*w[1] + xs[li+2][col]*w[2];
  }
  part[li][h][cq] = acc;
  __syncthreads();
  if (tid < 64) {
    const int l2 = tid >> 3, h2 = tid & 7;
    const float s = cb[h2] + part[l2][h2][0] + part[l2][h2][1]
                           + part[l2][h2][2] + part[l2][h2][3];
    sal[(size_t)(b*NH_ + h2) * L_ + l0 + l2] = s;
  }
}

// ---------------------------------------------------------------------------
// MFMA attention v5: zero barriers after sal staging; ALL K fragments come
// from fragment-native layouts (Kf/Gf) as fully coalesced base+lane*16B
// loads. Sweep1: kf reg-double-buffered. Sweep2: gf issued early (consumed
// after QK+store slack), kf prefetched. Ps same-wave LDS only.
// ---------------------------------------------------------------------------
__global__ __launch_bounds__(256) void attn_k(
    const u16* __restrict__ Qh, const u16* __restrict__ Kf,
    const u16* __restrict__ Gf, const float* __restrict__ sal,
    float* __restrict__ attn, u16* __restrict__ ctxb)
{
  __shared__ u16 Ps[64*72];
  __shared__ float sal_s[L_];

  const int tid = threadIdx.x;
  const int wid = tid >> 6, lane = tid & 63;
  const int lr = lane & 15, lg = lane >> 4;
  const int lin = blockIdx.x;
  const int swz = (lin & 7) * 64 + (lin >> 3);   // XCD-bijective (512 = 8*64)
  const int bh = swz >> 5, q0 = (swz & 31) << 6;

  const u16* Kfb = Kf + (size_t)bh * 131072;
  const u16* Gfb = Gf + (size_t)bh * 131072;

  {
    const float4* sp = (const float4*)(sal + (size_t)bh * L_);
    float4* dp = (float4*)sal_s;
#pragma unroll
    for (int i = 0; i < 2; ++i)
      dp[tid + i*256] = sp[tid + i*256];
  }
  const u16* Qp = Qh + ((size_t)bh * L_ + q0) * DH_;
  bf16x8 qf[2];
  qf[0] = *(const bf16x8*)(Qp + (size_t)(wid*16 + lr) * DH_ + lg*8);
  qf[1] = *(const bf16x8*)(Qp + (size_t)(wid*16 + lr) * DH_ + 32 + lg*8);
  __syncthreads();  // sal_s (only barrier in kernel)

  // ================= sweep 1: rowsums =================
  float rs[4] = {0.f, 0.f, 0.f, 0.f};
  {
    bf16x8 ka[8], kb[8];
#pragma unroll
    for (int f = 0; f < 8; ++f)
      ka[f] = *(const bf16x8*)(Kfb + ((size_t)((0*4 + (f>>1))*2 + (f&1))*64 + lane)*8);
#pragma unroll 2
    for (int t = 0; t < 32; ++t) {
      if (t < 31) {
#pragma unroll
        for (int f = 0; f < 8; ++f)
          kb[f] = *(const bf16x8*)(Kfb + ((size_t)(((t+1)*4 + (f>>1))*2 + (f&1))*64 + lane)*8);
      }
      const int m0 = t << 6;
#pragma unroll
      for (int ms = 0; ms < 4; ++ms) {
        f32x4 acc = {0.f, 0.f, 0.f, 0.f};
        acc = __builtin_amdgcn_mfma_f32_16x16x32_bf16(qf[0], ka[ms*2+0], acc, 0, 0, 0);
        acc = __builtin_amdgcn_mfma_f32_16x16x32_bf16(qf[1], ka[ms*2+1], acc, 0, 0, 0);
        const float sl = sal_s[m0 + ms*16 + lr];
#pragma unroll
        for (int r = 0; r < 4; ++r)
          rs[r] += __expf(fmaf(acc[r], 0.125f, sl));
      }
#pragma unroll
      for (int f = 0; f < 8; ++f) ka[f] = kb[f];
    }
  }
#pragma unroll
  for (int r = 0; r < 4; ++r) {
    float v = rs[r];
    v += __shfl_xor(v, 1); v += __shfl_xor(v, 2);
    v += __shfl_xor(v, 4); v += __shfl_xor(v, 8);
    rs[r] = 1.0f / v;
  }

  // ================= sweep 2: attn store + PV =================
  f32x4 pvacc[4] = {{0.f,0.f,0.f,0.f},{0.f,0.f,0.f,0.f},
                    {0.f,0.f,0.f,0.f},{0.f,0.f,0.f,0.f}};
  {
    bf16x8 ka[8], kb[8], g[8];
#pragma unroll
    for (int f = 0; f < 8; ++f)
      ka[f] = *(const bf16x8*)(Kfb + ((size_t)((0*4 + (f>>1))*2 + (f&1))*64 + lane)*8);
#pragma unroll 2
    for (int t = 0; t < 32; ++t) {
      const int m0 = t << 6;
      // gf issued first-thing: consumed only after QK+exp+store slack
#pragma unroll
      for (int f = 0; f < 8; ++f)
        g[f] = *(const bf16x8*)(Gfb + ((size_t)(((f>>1)*32 + t)*2 + (f&1))*64 + lane)*8);
      if (t < 31) {
#pragma unroll
        for (int f = 0; f < 8; ++f)
          kb[f] = *(const bf16x8*)(Kfb + ((size_t)(((t+1)*4 + (f>>1))*2 + (f&1))*64 + lane)*8);
      }
      // QK^T + normalized p -> Ps (same-wave strip)
#pragma unroll
      for (int ms = 0; ms < 4; ++ms) {
        f32x4 acc = {0.f, 0.f, 0.f, 0.f};
        acc = __builtin_amdgcn_mfma_f32_16x16x32_bf16(qf[0], ka[ms*2+0], acc, 0, 0, 0);
        acc = __builtin_amdgcn_mfma_f32_16x16x32_bf16(qf[1], ka[ms*2+1], acc, 0, 0, 0);
        const float sl = sal_s[m0 + ms*16 + lr];
#pragma unroll
        for (int r = 0; r < 4; ++r) {
          const float ph = __expf(fmaf(acc[r], 0.125f, sl)) * rs[r];
          Ps[(wid*16 + lg*4 + r)*72 + ms*16 + lr] = f2bf(ph);
        }
      }
      // attn store: own strip from Ps, coalesced float4 stores
      {
        const int qr = lane >> 2;
        const int mseg = (lane & 3) << 4;
        bf16x8 v0 = *(bf16x8*)&Ps[(wid*16 + qr)*72 + mseg];
        bf16x8 v1 = *(bf16x8*)&Ps[(wid*16 + qr)*72 + mseg + 8];
        float* dst = attn + ((size_t)bh * L_ + q0 + wid*16 + qr) * L_ + m0 + mseg;
#pragma unroll
        for (int u = 0; u < 2; ++u) {
          bf16x8 v = u ? v1 : v0;
          float4 f0 = make_float4(bf2f((u16)v[0]), bf2f((u16)v[1]),
                                  bf2f((u16)v[2]), bf2f((u16)v[3]));
          float4 f1 = make_float4(bf2f((u16)v[4]), bf2f((u16)v[5]),
                                  bf2f((u16)v[6]), bf2f((u16)v[7]));
          *(float4*)(dst + u*8)     = f0;
          *(float4*)(dst + u*8 + 4) = f1;
        }
      }
      // PV: ctx += P @ K
#pragma unroll
      for (int ks = 0; ks < 2; ++ks) {
        bf16x8 pa = *(bf16x8*)&Ps[(wid*16 + lr)*72 + ks*32 + lg*8];
#pragma unroll
        for (int ds = 0; ds < 4; ++ds)
          pvacc[ds] = __builtin_amdgcn_mfma_f32_16x16x32_bf16(pa, g[ds*2+ks], pvacc[ds], 0, 0, 0);
      }
#pragma unroll
      for (int f = 0; f < 8; ++f) ka[f] = kb[f];
    }
  }
  // ctx store [b, l, h*64+d] as bf16
  const int b = bh >> 3, h = bh & 7;
#pragma unroll
  for (int ds = 0; ds < 4; ++ds)
#pragma unroll
    for (int r = 0; r < 4; ++r)
      ctxb[((size_t)(b*L_ + q0 + wid*16 + lg*4 + r)) * DC_ + h*DH_ + ds*16 + lr] =
          f2bf(pvacc[ds][r]);
}

// ---------------------------------------------------------------------------
extern "C" void kernel_launch(void* const* d_in, const int* in_sizes, int n_in,
                              void* d_out, int out_size, void* d_ws, size_t ws_size,
                              hipStream_t stream)
{
  const float* src   = (const float*)d_in[0];
  const float* Wq    = (const float*)d_in[1];
  const float* bq    = (const float*)d_in[2];
  const float* Wk    = (const float*)d_in[3];
  const float* bk    = (const float*)d_in[4];
  const float* convw = (const float*)d_in[5];
  const float* convb = (const float*)d_in[6];
  const float* Wst   = (const float*)d_in[7];
  const float* bst   = (const float*)d_in[8];
  const float* Wout  = (const float*)d_in[9];
  const float* bout  = (const float*)d_in[10];

  float* out  = (float*)d_out;                 // fp32
  float* attn = out + (size_t)MR_ * DM_;

  u16*   x1b   = (u16*)d_ws;                    // [4096][512]
  u16*   Kh    = x1b   + (size_t)MR_ * DC_;     // K heads; becomes Kf in place
  u16*   Qh    = Kh    + (size_t)BH_ * L_ * DH_;
  u16*   Gf    = Qh    + (size_t)BH_ * L_ * DH_;// [16][4][32][2][64][8]
  u16*   ctxb  = Gf    + (size_t)BH_ * L_ * DH_;// [4096][512]
  u16*   y2b   = ctxb  + (size_t)MR_ * DC_;     // [4096][512]
  u16*   Wqb   = y2b   + (size_t)MR_ * DC_;     // [512][512]
  u16*   Wkb   = Wqb   + (size_t)DC_ * DC_;
  u16*   Wstb  = Wkb   + (size_t)DC_ * DC_;
  u16*   Woutb = Wstb  + (size_t)DC_ * DC_;     // [1024][1024]
  float* salb  = (float*)(Woutb + (size_t)DM_ * DM_); // [16][2048]

  (void)in_sizes; (void)n_in; (void)out_size; (void)ws_size;

  cvt_k<<<dim3(3840), 256, 0, stream>>>(src, Wq, Wk, Wst, Wout,
                                        x1b, Wqb, Wkb, Wstb, Woutb);
  mgemm_k<0,64><<<dim3(8, 32), 256, 0, stream>>>(x1b, nullptr, Wqb, bq, nullptr, Qh, nullptr, DC_, DC_);
  mgemm_k<0,64><<<dim3(8, 32), 256, 0, stream>>>(x1b, nullptr, Wkb, bk, nullptr, Kh, nullptr, DC_, DC_);
  frag_k<<<dim3(512), 256, 0, stream>>>(Kh, Kh /*in-place Kf*/, Gf);
  conv_k<<<dim3(L_/8, B_), 256, 0, stream>>>(src, convw, convb, salb);
  attn_k<<<dim3(512), 256, 0, stream>>>(Qh, Kh /*Kf*/, Gf, salb, attn, ctxb);
  mgemm_k<1,64><<<dim3(8, 32), 256, 0, stream>>>(ctxb, nullptr, Wstb, bst, src, y2b, nullptr, DC_, DC_);
  mgemm_k<2,128><<<dim3(8, 32), 256, 0, stream>>>(x1b, y2b, Woutb, bout, nullptr, nullptr, out, DM_, DM_);
}